// Round 11
// baseline (190.604 us; speedup 1.0000x reference)
//
#include <hip/hip_runtime.h>
#include <hip/hip_bf16.h>

#define D_MODEL 1024
#define NHEAD   16
#define HDIM    64
#define SEQQ    2048
#define NBATCH  2
#define MROWS   (NBATCH * SEQQ)   // 4096

typedef unsigned short u16;
typedef __attribute__((ext_vector_type(8))) short short8;    // 8 bf16 (4 VGPRs)
typedef __attribute__((ext_vector_type(4))) short bf16x4;    // 4 bf16 (2 VGPRs)
typedef __attribute__((ext_vector_type(4))) float floatx4;   // 4 fp32
typedef __attribute__((ext_vector_type(16))) float floatx16; // 32x32 MFMA acc

__device__ __forceinline__ u16 f2b(float f) {
    union { __hip_bfloat16 h; u16 u; } cv;
    cv.h = __float2bfloat16(f);
    return cv.u;
}
__device__ __forceinline__ float b2f(u16 u) {
    return __uint_as_float(((unsigned int)u) << 16);
}
__device__ __forceinline__ short8 load8(const u16* p) {
    return *reinterpret_cast<const short8*>(p);
}
__device__ __forceinline__ bf16x4 load4v(const u16* p) {
    return *reinterpret_cast<const bf16x4*>(p);
}
__device__ __forceinline__ unsigned pack2(float lo, float hi) {
    return ((unsigned)f2b(hi) << 16) | (unsigned)f2b(lo);
}
__device__ __forceinline__ void async_cp16(const void* g, void* l) {
    __builtin_amdgcn_global_load_lds(
        (const __attribute__((address_space(1))) void*)g,
        (__attribute__((address_space(3))) void*)l, 16, 0, 0);
}

// ---------------- fp32 -> bf16 convert + RoPE cos/sin table, one dispatch ----------------
// z 0..3: X quarters (flat). z 4..5: Wq/Wk with per-head row DE-INTERLEAVE
// (out row position q<32 of a head holds feature 2q; position 32+q holds
// feature 2q+1) -> rope partners land in the SAME LANE, same reg, adjacent
// 32-col tile in the 32x32-MFMA gemm epilogue. z=6..7: Wv/Wo flat.
// z=8: rope table tab[j*SEQQ+s]=(cos,sin).
__global__ void cvt_all(const float* __restrict__ X,
                        const float* __restrict__ w0, const float* __restrict__ w1,
                        const float* __restrict__ w2, const float* __restrict__ w3,
                        const int* __restrict__ pos,
                        u16* __restrict__ xo,
                        u16* __restrict__ o0, u16* __restrict__ o1,
                        u16* __restrict__ o2, u16* __restrict__ o3,
                        float2* __restrict__ tab) {
    const int z = blockIdx.y;
    const int i = blockIdx.x * 256 + threadIdx.x;
    if (z == 8) {
        if (i < SEQQ * 32) {
            const int j = i >> 11, s = i & (SEQQ - 1);
            const float p = (float)pos[s];
            const float inv = expf(-(float)j * (9.210340371976184f / 32.0f));
            float sn, cs;
            sincosf(p * inv, &sn, &cs);
            tab[i] = make_float2(cs, sn);
        }
        return;
    }
    const int n4 = (D_MODEL * D_MODEL) / 4;
    const float* in;
    u16* out;
    if (z < 4) { in = X + (size_t)z * n4 * 4;  out = xo + (size_t)z * n4 * 4; }
    else {
        in  = (z == 4) ? w0 : (z == 5) ? w1 : (z == 6) ? w2 : w3;
        out = (z == 4) ? o0 : (z == 5) ? o1 : (z == 6) ? o2 : o3;
    }
    int src = i;
    if (z == 4 || z == 5) {
        const int orow = i >> 8;            // out weight row (256 float4 / row)
        const int g    = i & 255;
        const int irow = (orow & ~63) | (((orow & 31) << 1) | ((orow >> 5) & 1));
        src = irow * 256 + g;
    }
    float4 v = reinterpret_cast<const float4*>(in)[src];
    ushort4 o;
    o.x = f2b(v.x); o.y = f2b(v.y); o.z = f2b(v.z); o.w = f2b(v.w);
    reinterpret_cast<ushort4*>(out)[i] = o;
}

// ---------------- merged QKV GEMM v7: 32x32x16 MFMA (halved instruction count) ----------------
// R8/R9/R10 invariant: 19.5 cy per MFMA INSTRUCTION per CU across occupancy
// 3->6 blk/CU, prefetch depth, swizzle, and 8->24 MFMA/barrier -> cost is
// per-instruction. v7 switches to mfma_f32_32x32x16_bf16: 2x FLOP per instr,
// same LDS bytes per instr -> instruction count halves (12 vs 24 per
// wave-iter). Layouts: A row=lane&31, k=8*(lane>>5)+[0..8); B col likewise
// (generalizes the verified 16x16 pattern); C/D col=lane&31,
// row=(reg&3)+8*(reg>>2)+4*(lane>>5) [guide m74/m101].
// Wave = 32 rows x 64 cols (2 col-tiles): rope partner = same lane/reg,
// other col-tile (de-interleaved weights). Structure else unchanged:
// 64x128 tile, dbuf, vmcnt(0)+single barrier, grid (64,8).
__global__ __launch_bounds__(256, 2) void gemm_qkv(
    const u16* __restrict__ A,
    const u16* __restrict__ B0, const u16* __restrict__ B1, const u16* __restrict__ B2,
    u16* __restrict__ Qt, u16* __restrict__ Kt, u16* __restrict__ Vt,
    const float2* __restrict__ tab)
{
    const int K = D_MODEL;

    __shared__ __attribute__((aligned(16))) u16 As[2][64 * 32];        // 8 KB
    __shared__ __attribute__((aligned(16))) u16 Bs[2][3][128 * 32];    // 48 KB

    const int tid  = threadIdx.x;
    const int w    = tid >> 6;
    const int lane = tid & 63;
    const int l31  = lane & 31;
    const int hk   = lane >> 5;         // k-half selector for 32x32 frags
    const int wm   = w >> 1, wn = w & 1;
    const int tm   = blockIdx.x * 64, tn = blockIdx.y * 128;

    floatx16 acc[3][2];
#pragma unroll
    for (int zz = 0; zz < 3; zz++)
#pragma unroll
        for (int ni = 0; ni < 2; ni++)
            acc[zz][ni] = (floatx16){};

    const int srow = lane >> 2;
    const int scol = (lane & 3) * 8;

    // per thread per stage: 1 A-chunk + 3x2 B-chunks = 7 async_cp16
    auto stage = [&](int buf, int k0) {
        async_cp16(A + (size_t)(tm + w * 16 + srow) * K + k0 + scol, &As[buf][w * 512]);
#pragma unroll
        for (int ch = w; ch < 8; ch += 4) {
            async_cp16(B0 + (size_t)(tn + ch * 16 + srow) * K + k0 + scol, &Bs[buf][0][ch * 512]);
            async_cp16(B1 + (size_t)(tn + ch * 16 + srow) * K + k0 + scol, &Bs[buf][1][ch * 512]);
            async_cp16(B2 + (size_t)(tn + ch * 16 + srow) * K + k0 + scol, &Bs[buf][2][ch * 512]);
        }
    };

    stage(0, 0);

    for (int kt = 0; kt < 32; ++kt) {
        asm volatile("s_waitcnt vmcnt(0)" ::: "memory");
        __builtin_amdgcn_s_barrier();
        if (kt < 31) stage((kt + 1) & 1, (kt + 1) * 32);

        const int buf = kt & 1;
        // A-frags: row = wm*32 + l31, k-halves 0/1 within BK=32
        short8 af0 = load8(&As[buf][(wm * 32 + l31) * 32 + 0 * 16 + hk * 8]);
        short8 af1 = load8(&As[buf][(wm * 32 + l31) * 32 + 1 * 16 + hk * 8]);

#pragma unroll
        for (int zz = 0; zz < 3; zz++) {
            short8 b00 = load8(&Bs[buf][zz][(wn * 64 +  0 + l31) * 32 + 0 * 16 + hk * 8]);
            short8 b01 = load8(&Bs[buf][zz][(wn * 64 +  0 + l31) * 32 + 1 * 16 + hk * 8]);
            short8 b10 = load8(&Bs[buf][zz][(wn * 64 + 32 + l31) * 32 + 0 * 16 + hk * 8]);
            short8 b11 = load8(&Bs[buf][zz][(wn * 64 + 32 + l31) * 32 + 1 * 16 + hk * 8]);
            acc[zz][0] = __builtin_amdgcn_mfma_f32_32x32x16_bf16(af0, b00, acc[zz][0], 0, 0, 0);
            acc[zz][0] = __builtin_amdgcn_mfma_f32_32x32x16_bf16(af1, b01, acc[zz][0], 0, 0, 0);
            acc[zz][1] = __builtin_amdgcn_mfma_f32_32x32x16_bf16(af0, b10, acc[zz][1], 0, 0, 0);
            acc[zz][1] = __builtin_amdgcn_mfma_f32_32x32x16_bf16(af1, b11, acc[zz][1], 0, 0, 0);
        }
    }

    // C/D mapping: col = l31 (within 32-tile), row = (reg&3) + 8*(reg>>2) + 4*hk
    const int hh = (tn >> 6) + wn;          // head index, constant per thread

    // ---- epilogue 1: V transpose store [b,h,d,s] ----
#pragma unroll
    for (int ni = 0; ni < 2; ni++) {
        const int d = ni * 32 + l31;        // feature within head (V not de-interleaved)
#pragma unroll
        for (int g = 0; g < 4; g++) {
            const int r0 = tm + wm * 32 + g * 8 + hk * 4;
            const int bb = r0 >> 11, s0 = r0 & (SEQQ - 1);
            ushort4 pk;
            pk.x = f2b(acc[2][ni][g * 4 + 0]);
            pk.y = f2b(acc[2][ni][g * 4 + 1]);
            pk.z = f2b(acc[2][ni][g * 4 + 2]);
            pk.w = f2b(acc[2][ni][g * 4 + 3]);
            *reinterpret_cast<ushort4*>(
                &Vt[(((size_t)(bb * NHEAD + hh)) * HDIM + d) * SEQQ + s0]) = pk;
        }
    }

    // ---- epilogue 2+3: Q and K rope ----
    // De-interleaved: even-feature slot = col-tile 0, odd = col-tile 1, same
    // lane & reg. qq = l31 = freq index. Store (re,ro) as one u32 at natural
    // d-order (2qq, 2qq+1).
#pragma unroll
    for (int zz = 0; zz < 2; zz++) {
        const float qsc = (zz == 0) ? 0.18033688011112042f : 1.0f;  // 0.125*log2(e) | 1
        u16* Outp = (zz == 0) ? Qt : Kt;
        float4 ta[2], tb[2];
        auto ldtab = [&](int g) {
            const int s0 = (tm + wm * 32 + g * 8 + hk * 4) & (SEQQ - 1);
            ta[g & 1] = *reinterpret_cast<const float4*>(&tab[l31 * SEQQ + s0]);
            tb[g & 1] = *reinterpret_cast<const float4*>(&tab[l31 * SEQQ + s0 + 2]);
        };
        ldtab(0);
#pragma unroll
        for (int g = 0; g < 4; ++g) {
            if (g < 3) ldtab(g + 1);        // issue next group's loads early
            const int r0 = tm + wm * 32 + g * 8 + hk * 4;
            const int bb = r0 >> 11, s0 = r0 & (SEQQ - 1);
            const float4 A4 = ta[g & 1], B4 = tb[g & 1];
            const float cs[4] = {A4.x, A4.z, B4.x, B4.z};
            const float sn[4] = {A4.y, A4.w, B4.y, B4.w};
#pragma unroll
            for (int j = 0; j < 4; j++) {
                const float e = acc[zz][0][g * 4 + j];
                const float o = acc[zz][1][g * 4 + j];
                const unsigned val =
                    (unsigned)f2b((e * cs[j] - o * sn[j]) * qsc) |
                    ((unsigned)f2b((e * sn[j] + o * cs[j]) * qsc) << 16);
                *reinterpret_cast<unsigned*>(
                    &Outp[(((size_t)(bb * NHEAD + hh)) * SEQQ + (s0 + j)) * HDIM + 2 * l31]) = val;
            }
        }
    }
}

// ---------------- causal flash attention v13 (unchanged) ----------------
__global__ __launch_bounds__(256, 4) void attn_kernel(
    const u16* __restrict__ Qt, const u16* __restrict__ Kt, const u16* __restrict__ Vt,
    u16* __restrict__ Out)
{
    const int bid = blockIdx.x;
    const int xcd = bid & 7;
    const int u   = bid >> 3;               // 0..127 within XCD
    const int col = xcd * 4 + (u & 3);      // (b,h) column 0..31, 4 per XCD
    const int m   = u >> 2;                 // 0..31
    int qsub;
    if      (m < 8)  qsub = 31 - m;
    else if (m < 16) qsub = m - 8;
    else if (m < 24) qsub = 39 - m;
    else             qsub = m - 16;
    const int h = col & (NHEAD - 1), b = col >> 4;

    const int tid = threadIdx.x, w = tid >> 6, lane = tid & 63;
    const int l15 = lane & 15, quad = lane >> 4;
    const size_t bh = (size_t)(b * NHEAD + h);
    const u16* Qh = Qt + bh * SEQQ * HDIM;
    const u16* Kh = Kt + bh * SEQQ * HDIM;
    const u16* Vh = Vt + bh * HDIM * SEQQ;   // [d][s]

    __shared__ __attribute__((aligned(16))) u16 Ks[2][64 * 64];   // 16 KB
    __shared__ __attribute__((aligned(16))) u16 Vs[2][64 * 64];   // 16 KB

    short8 ones;
#pragma unroll
    for (int i = 0; i < 8; i++) ones[i] = (short)0x3F80;  // bf16 1.0

    // staging: each of 4 waves stages 2 K-chunks + 2 V-chunks (1 KB each)
    const int rr  = lane >> 3;                 // 0..7
    const int swz = ((lane & 7) ^ rr) * 8;     // XOR-swizzled col offset (u16)
    auto stage = [&](int buf, int tt) {
        const int k0s = tt * 64;
        async_cp16(Kh + (size_t)(k0s + w * 8 + rr) * HDIM + swz,       &Ks[buf][w * 512]);
        async_cp16(Kh + (size_t)(k0s + (w + 4) * 8 + rr) * HDIM + swz, &Ks[buf][(w + 4) * 512]);
        async_cp16(Vh + (size_t)(w * 8 + rr) * SEQQ + k0s + swz,       &Vs[buf][w * 512]);
        async_cp16(Vh + (size_t)((w + 4) * 8 + rr) * SEQQ + k0s + swz, &Vs[buf][(w + 4) * 512]);
    };

    const int s7  = l15 & 7;
    const int sw1 = ((quad)     ^ s7) * 8;     // K dims chunk 0..31
    const int sw2 = ((quad + 4) ^ s7) * 8;     // K dims chunk 32..63
    // V b64 element offsets for permuted PV k-slots (chunk*8 + (quad&1)*4):
    const int vo0 = (((quad >> 1)    ) ^ s7) * 8 + (quad & 1) * 4;  // keys  4*quad..
    const int vo1 = (((quad >> 1) + 2) ^ s7) * 8 + (quad & 1) * 4;  // keys 16+4*quad..
    const int vo2 = (((quad >> 1) + 4) ^ s7) * 8 + (quad & 1) * 4;  // keys 32+4*quad..
    const int vo3 = (((quad >> 1) + 6) ^ s7) * 8 + (quad & 1) * 4;  // keys 48+4*quad..

    const int q0w   = qsub * 64 + w * 16;      // this wave's 16 q-rows
    const int tmaxp = qsub;                    // diag tile, same for all 4 waves

    // Q fragment loads FIRST (drained together with stage(0) by first vmcnt(0))
    short8 qf[2];
#pragma unroll
    for (int kk = 0; kk < 2; kk++)
        qf[kk] = load8(&Qh[(size_t)(q0w + l15) * HDIM + kk * 32 + quad * 8]);

    floatx4 O[4];
    floatx4 l_acc = {0.f, 0.f, 0.f, 0.f};
#pragma unroll
    for (int c = 0; c < 4; c++) { floatx4 zz = {0.f, 0.f, 0.f, 0.f}; O[c] = zz; }

    stage(0, 0);

    for (int t = 0; t <= tmaxp; ++t) {
        // stage(t) (4 DMAs, issued one full tile-compute ago) must be complete
        asm volatile("s_waitcnt vmcnt(0)" ::: "memory");
        __builtin_amdgcn_s_barrier();
        if (t < tmaxp) stage((t + 1) & 1, t + 1);   // prefetch distance 1

        const u16* KsB = &Ks[t & 1][0];
        const u16* VsB = &Vs[t & 1][0];
        const int k0 = t * 64;

        // S^T[c]: rows = key_local (c*16 + quad*4 + r), cols = q (l15)
        floatx4 S[4];
        __builtin_amdgcn_s_setprio(1);
#pragma unroll
        for (int c = 0; c < 4; c++) {
            const int rowb = (c * 16 + l15) * 64;
            floatx4 zz = {0.f, 0.f, 0.f, 0.f};
            S[c] = __builtin_amdgcn_mfma_f32_16x16x32_bf16(load8(&KsB[rowb + sw1]), qf[0], zz,   0, 0, 0);
            S[c] = __builtin_amdgcn_mfma_f32_16x16x32_bf16(load8(&KsB[rowb + sw2]), qf[1], S[c], 0, 0, 0);
        }
        __builtin_amdgcn_s_setprio(0);

        if (t == tmaxp) {
            const int q = q0w + l15;
#pragma unroll
            for (int c = 0; c < 4; c++)
#pragma unroll
                for (int r = 0; r < 4; r++)
                    if (k0 + c * 16 + quad * 4 + r > q) S[c][r] = -1e30f;
        }

#pragma unroll
        for (int c = 0; c < 4; c++)
#pragma unroll
            for (int r = 0; r < 4; r++)
                S[c][r] = __builtin_amdgcn_exp2f(S[c][r]);

        // ---- pack P into PV A-fragments (lane-local, permuted k-slots) ----
        union { short8 v; unsigned u[4]; } pf0, pf1;
        pf0.u[0] = pack2(S[0][0], S[0][1]);
        pf0.u[1] = pack2(S[0][2], S[0][3]);
        pf0.u[2] = pack2(S[1][0], S[1][1]);
        pf0.u[3] = pack2(S[1][2], S[1][3]);
        pf1.u[0] = pack2(S[2][0], S[2][1]);
        pf1.u[1] = pack2(S[2][2], S[2][3]);
        pf1.u[2] = pack2(S[3][0], S[3][1]);
        pf1.u[3] = pack2(S[3][2], S[3][3]);

        __builtin_amdgcn_s_setprio(1);
        l_acc = __builtin_amdgcn_mfma_f32_16x16x32_bf16(pf0.v, ones, l_acc, 0, 0, 0);
        l_acc = __builtin_amdgcn_mfma_f32_16x16x32_bf16(pf1.v, ones, l_acc, 0, 0, 0);

#pragma unroll
        for (int c2 = 0; c2 < 4; c2++) {
            const int rowb = (c2 * 16 + l15) * 64;
            bf16x4 a0 = load4v(&VsB[rowb + vo0]);
            bf16x4 a1 = load4v(&VsB[rowb + vo1]);
            bf16x4 a2 = load4v(&VsB[rowb + vo2]);
            bf16x4 a3 = load4v(&VsB[rowb + vo3]);
            short8 v0 = __builtin_shufflevector(a0, a1, 0, 1, 2, 3, 4, 5, 6, 7);
            short8 v1 = __builtin_shufflevector(a2, a3, 0, 1, 2, 3, 4, 5, 6, 7);
            O[c2] = __builtin_amdgcn_mfma_f32_16x16x32_bf16(pf0.v, v0, O[c2], 0, 0, 0);
            O[c2] = __builtin_amdgcn_mfma_f32_16x16x32_bf16(pf1.v, v1, O[c2], 0, 0, 0);
        }
        __builtin_amdgcn_s_setprio(0);
    }

    float inv_l[4];
#pragma unroll
    for (int r = 0; r < 4; r++) inv_l[r] = 1.0f / l_acc[r];

#pragma unroll
    for (int c2 = 0; c2 < 4; c2++)
#pragma unroll
        for (int r = 0; r < 4; r++) {
            const int q    = q0w + quad * 4 + r;
            const int colo = h * HDIM + c2 * 16 + l15;
            Out[(size_t)(b * SEQQ + q) * D_MODEL + colo] = f2b(O[c2][r] * inv_l[r]);
        }
}

// ---------------- o-proj GEMM v3: 32x32x16 MFMA, 64x64 tile, 1024 blocks ----------------
// Same instruction-halving as gemm_qkv: per wave-iter 2 MFMA (was 8), one
// 32x32 output tile per wave. Triple-buffer counted-vmcnt schedule kept.
__global__ __launch_bounds__(256) void gemm_o(
    const u16* __restrict__ A, const u16* __restrict__ Bt, float* __restrict__ C)
{
    const int K = D_MODEL, N = D_MODEL;
    __shared__ __attribute__((aligned(16))) u16 As[3][64 * 32];
    __shared__ __attribute__((aligned(16))) u16 Bs[3][64 * 32];

    const int tid  = threadIdx.x;
    const int w    = tid >> 6;
    const int lane = tid & 63;
    const int l31  = lane & 31;
    const int hk   = lane >> 5;
    const int wm   = w >> 1, wn = w & 1;
    const int tm   = blockIdx.x * 64, tn = blockIdx.y * 64;

    floatx16 acc = (floatx16){};

    const int srow = lane >> 2;
    const int scol = (lane & 3) * 8;

    auto stage = [&](int buf, int k0) {
        async_cp16(A  + (size_t)(tm + w * 16 + srow) * K + k0 + scol, &As[buf][w * 512]);
        async_cp16(Bt + (size_t)(tn + w * 16 + srow) * K + k0 + scol, &Bs[buf][w * 512]);
    };

    stage(0, 0);
    stage(1, 32);

    for (int kt = 0; kt < 32; ++kt) {
        if (kt < 30) asm volatile("s_waitcnt vmcnt(2)" ::: "memory");
        else         asm volatile("s_waitcnt vmcnt(0)" ::: "memory");
        __builtin_amdgcn_s_barrier();
        if (kt < 30) stage((kt + 2) % 3, (kt + 2) * 32);

        const u16* AsB = &As[kt % 3][0];
        const u16* BsB = &Bs[kt % 3][0];

        short8 af0 = load8(&AsB[(wm * 32 + l31) * 32 + 0 * 16 + hk * 8]);
        short8 af1 = load8(&AsB[(wm * 32 + l31) * 32 + 1 * 16 + hk * 8]);
        short8 bf0 = load8(&BsB[(wn * 32 + l31) * 32 + 0 * 16 + hk * 8]);
        short8 bf1 = load8(&BsB[(wn * 32 + l31) * 32 + 1 * 16 + hk * 8]);
        acc = __builtin_amdgcn_mfma_f32_32x32x16_bf16(af0, bf0, acc, 0, 0, 0);
        acc = __builtin_amdgcn_mfma_f32_32x32x16_bf16(af1, bf1, acc, 0, 0, 0);
    }

    // C/D: col = l31, row = (reg&3) + 8*(reg>>2) + 4*hk
    const int colo = tn + wn * 32 + l31;
#pragma unroll
    for (int g = 0; g < 4; g++) {
        const int row = tm + wm * 32 + g * 8 + hk * 4;
#pragma unroll
        for (int j = 0; j < 4; j++)
            C[(size_t)(row + j) * N + colo] = acc[g * 4 + j];
    }
}

// ---------------- launch ----------------
extern "C" void kernel_launch(void* const* d_in, const int* in_sizes, int n_in,
                              void* d_out, int out_size, void* d_ws, size_t ws_size,
                              hipStream_t stream)
{
    const float* X  = (const float*)d_in[0];
    const float* Wq = (const float*)d_in[1];
    const float* Wk = (const float*)d_in[2];
    const float* Wv = (const float*)d_in[3];
    const float* Wo = (const float*)d_in[4];
    const int* tpos = (const int*)d_in[5];
    float* out = (float*)d_out;
    char* ws = (char*)d_ws;

    const size_t MB = (size_t)1 << 20;
    u16*    Xb  = (u16*)(ws + 0);        // 8 MB bf16 X
    u16*    WqB = (u16*)(ws + 8 * MB);
    u16*    WkB = (u16*)(ws + 10 * MB);
    u16*    WvB = (u16*)(ws + 12 * MB);
    u16*    WoB = (u16*)(ws + 14 * MB);
    float2* tab = (float2*)(ws + 16 * MB);  // 512 KB rope table (j-major)
    u16*    Qt  = (u16*)(ws + 24 * MB);
    u16*    Kt  = (u16*)(ws + 32 * MB);
    u16*    Vt  = (u16*)(ws + 40 * MB);
    u16*   AOut = (u16*)(ws + 48 * MB);

    cvt_all<<<dim3(1024, 9), 256, 0, stream>>>(X, Wq, Wk, Wv, Wo, tpos,
                                               Xb, WqB, WkB, WvB, WoB, tab);

    gemm_qkv<<<dim3(64, 8), 256, 0, stream>>>(Xb, WqB, WkB, WvB,
                                              Qt, Kt, Vt, tab);
    attn_kernel<<<dim3(1024, 1, 1), 256, 0, stream>>>(Qt, Kt, Vt, AOut);
    gemm_o<<<dim3(64, 16), 256, 0, stream>>>(AOut, WoB, out);
}